// Round 14
// baseline (379.770 us; speedup 1.0000x reference)
//
#include <hip/hip_runtime.h>
#include <hip/hip_bf16.h>

#define EMB 128

typedef __attribute__((ext_vector_type(8))) short short8;   // 8 bf16 (4 VGPRs)
typedef __attribute__((ext_vector_type(4))) float floatx4;  // MFMA C/D
typedef __attribute__((ext_vector_type(2))) float v2f;      // -> v_pk_fma_f32

// 26 valid (ok, di, ol) message combos: deltas = {1,2,-1,-2}, ol = ok+delta in [0,8)
static constexpr int OKv[26] = {0,0,1,1,1,2,2,2,2,3,3,3,3,4,4,4,4,5,5,5,5,6,6,6,7,7};
static constexpr int DIv[26] = {0,1,0,1,2,0,1,2,3,0,1,2,3,0,1,2,3,0,1,2,3,0,2,3,2,3};
static constexpr int OLv[26] = {1,2,2,3,0,3,4,1,0,4,5,2,1,5,6,3,2,6,7,4,3,7,5,4,6,5};

__device__ __forceinline__ v2f ldv2(const float* p) { return *(const v2f*)p; }

// round-to-nearest-even bf16 bits of x, kept in the TOP 16 bits (low 16 zero)
__device__ __forceinline__ unsigned bf16_rne_hi(float x) {
  unsigned u = __float_as_uint(x);
  return (u + 0x7FFFu + ((u >> 16) & 1u)) & 0xFFFF0000u;
}
__device__ __forceinline__ float bf16hi_f(float x) {
  return __uint_as_float(bf16_rne_hi(x));
}
// HW packed cvt: a -> low 16, b -> high 16 (v_cvt_pk_bf16_f32 on gfx950)
__device__ __forceinline__ unsigned cvt_pk_bf16(float a, float b) {
  __hip_bfloat162 h = __float22bfloat162_rn(make_float2(a, b));
  unsigned r; __builtin_memcpy(&r, &h, 4); return r;
}

union FragU { unsigned u[4]; uint4 q; short8 v; };

// LOGICAL CHANNEL PERMUTATION (R9-verified): MFMA C physical position
// (u, n=lane&15) carries logical channel L(u,n) = 2*((u>>1)*16 + n) + (u&1).
// Wave wv computes u in {2wv, 2wv+1} -> lane (wv, m16) holds the ADJACENT
// logical pair c0 = 2*(wv*16+m16), c0+1. Only wfrag bakes the permutation.

// Fused prep, grid 73 x 512:
//  b 0..31  : lin32 row b (4-way f-split + LDS reduce)
//  b 32..71 : w_conv -> B-fragment hi/lo pre-pack with permuted N
//  b 72     : out[g] = b_pred[0]
__global__ __launch_bounds__(512) void prep_kernel(
    const float* __restrict__ emb_x,
    const float* __restrict__ w_ti,
    const float* __restrict__ b_ti,
    const float* __restrict__ w_conv,
    const float* __restrict__ b_pred,
    float* __restrict__ lin32,
    uint4* __restrict__ wfrag,
    float* __restrict__ out) {
  const int b = blockIdx.x, tid = threadIdx.x;
  if (b < 32) {
    __shared__ float red[4][EMB];
    const int e = tid & 127, fh = tid >> 7;      // fh in [0,4)
    const float* xr = emb_x + b * EMB;
    float s = 0.f;
    #pragma unroll 8
    for (int f = fh * 32; f < fh * 32 + 32; ++f)
      s = fmaf(xr[f], w_ti[f * EMB + e], s);
    red[fh][e] = s;
    __syncthreads();
    if (fh == 0)
      lin32[b * EMB + e] =
          b_ti[e] + ((red[0][e] + red[1][e]) + (red[2][e] + red[3][e]));
  } else if (b < 72) {
    const int id   = (b - 32) * 512 + tid;   // 320 frags * 64 lanes = 20480
    const int lane = id & 63;
    const int f    = id >> 6;
    const int pass = f & 1;           // 0 = hi, 1 = lo
    const int u    = (f >> 1) & 7;    // N-tile (physical)
    const int t    = (f >> 4) & 3;    // K-tile
    const int l    = f >> 6;          // layer
    const int q    = lane >> 4, n = lane & 15;
    const int cN   = 2 * ((u >> 1) * 16 + n) + (u & 1);   // logical out channel
    unsigned w[4] = {0u, 0u, 0u, 0u};
    #pragma unroll
    for (int j = 0; j < 8; ++j) {
      const int kk = t * 32 + q * 8 + j;    // logical in channel (canonical)
      float val = w_conv[l * (EMB * EMB) + kk * EMB + cN];
      if (pass) val = val - bf16hi_f(val);
      const unsigned bb = bf16_rne_hi(val);
      w[j >> 1] |= (j & 1) ? bb : (bb >> 16);
    }
    wfrag[id] = make_uint4(w[0], w[1], w[2], w[3]);
  } else {
    if (tid < 64) out[tid] = b_pred[0];
  }
}

// Block = TWO root nodes (i0=2b, i1=2b+1), phase-interleaved: while root A's
// MFMA phase waits on LDS/B-load latency, root B's independent message-pass
// VALU work fills the same barrier-free region (and vice versa). This targets
// the R13-measured structure: MFMA (24%) and VALU (29%) occupied disjoint
// timeline segments of each wave; all other resources were non-binding
// (R11: 2x blocks neutral; R12: prefetch neutral; R13: VALU -6pts neutral).
// One shared fragA buffer; 3 barriers per layer-pair (1.5/root-layer vs 2).
// No occupancy attribute (R1/R6: forced budgets -> 0.5-1.6 GB spills).
__global__ __launch_bounds__(256)
void i2gnn_mfma(
    const int* __restrict__ x,
    const int* __restrict__ edge_attr,
    const int* __restrict__ tuplefeat,
    const float* __restrict__ emb_x,
    const float* __restrict__ emb_tf,
    const float* __restrict__ emb_ea,
    const float* __restrict__ lin32,
    const float* __restrict__ b_conv,
    const float* __restrict__ w_pred,
    const uint4* __restrict__ wfrag,
    float* __restrict__ out)
{
  __shared__ __align__(16) unsigned fragA[2 * 64 * 68];   // 34816 B, lo at +4352

  const int tid = threadIdx.x;
  const int wv = tid >> 6, lane = tid & 63;
  const int m16 = lane & 15, q2 = lane >> 4;
  const int pc = wv * 16 + m16;        // logical pair-column this lane produces
  const int c0 = pc * 2;               // logical channels c0, c0+1

  const int i0 = blockIdx.x * 2;       // two roots, always same graph
  const int g  = i0 >> 6;

  // per-root constants
  int pkk[2][4];
  v2f xe[2];
  v2f lj[2][2];
  int tbase[2];
  #pragma unroll
  for (int r = 0; r < 2; ++r) {
    const int i = i0 + r;
    const int ibase = i & ~63, io = i & 63;
    unsigned p0 = 0, p1 = 0, p2 = 0, p3 = 0;
    #pragma unroll
    for (int m = 0; m < 26; ++m) {
      const int kg = ibase + ((io + OKv[m]) & 63);
      const unsigned a = (unsigned)edge_attr[(kg << 2) + DIv[m]];
      const unsigned sh = (m & 7) * 4;
      if ((m >> 3) == 0) p0 |= a << sh;
      else if ((m >> 3) == 1) p1 |= a << sh;
      else if ((m >> 3) == 2) p2 |= a << sh;
      else p3 |= a << sh;
    }
    // wave-uniform -> keep in SGPRs
    pkk[r][0] = __builtin_amdgcn_readfirstlane(p0);
    pkk[r][1] = __builtin_amdgcn_readfirstlane(p1);
    pkk[r][2] = __builtin_amdgcn_readfirstlane(p2);
    pkk[r][3] = __builtin_amdgcn_readfirstlane(p3);
    xe[r] = ldv2(emb_x + x[i] * EMB + c0);
    #pragma unroll
    for (int ps = 0; ps < 2; ++ps) {
      const int jn = ibase + ((io + 2 * q2 + ps) & 63);
      lj[r][ps] = ldv2(lin32 + x[jn] * EMB + c0);
    }
    tbase[r] = i * 64;
  }

  // X[r][mt][rr]: pair ps = mt&1 (lane's pairs 2q2, 2q2+1), k = (mt>>1)*4+rr
  v2f X[2][4][4];
  #pragma unroll
  for (int r = 0; r < 2; ++r)
    #pragma unroll
    for (int mt = 0; mt < 4; ++mt) {
      const int ps = mt & 1, kb = (mt >> 1) * 4;
      const int t0 = tbase[r] + (2 * q2 + ps) * 8;
      const v2f xl = xe[r] * lj[r][ps];
      #pragma unroll
      for (int rr = 0; rr < 4; ++rr) {
        const int2 tf2 = *(const int2*)(tuplefeat + 2 * (t0 + kb + rr));
        const int row = (c0 < 64) ? tf2.x : tf2.y;
        X[r][mt][rr] = xl * ldv2(emb_tf + row * 64 + (c0 & 63));
      }
    }

  // ---- phase helpers (inlined lambdas) ----
  auto msg = [&](int r, v2f acc[2][8]) {
    #pragma unroll
    for (int ps = 0; ps < 2; ++ps)
      #pragma unroll
      for (int k = 0; k < 8; ++k) acc[ps][k] = (v2f){0.f, 0.f};
    #pragma unroll
    for (int m = 0; m < 26; ++m) {
      const unsigned attr = ((unsigned)pkk[r][m >> 3] >> ((m & 7) * 4)) & 15u;
      const v2f e = ldv2(emb_ea + attr * EMB + c0);
      const int ok = OKv[m], ol = OLv[m];
      const int mtb = 2 * (ol >> 2), rl = ol & 3;
      acc[0][ok] += X[r][mtb + 0][rl] * e;
      acc[1][ok] += X[r][mtb + 1][rl] * e;
    }
  };
  auto pack = [&](v2f acc[2][8]) {
    #pragma unroll
    for (int ps = 0; ps < 2; ++ps)
      #pragma unroll
      for (int k = 0; k < 8; ++k) {
        const v2f a = acc[ps][k];
        const unsigned hi = cvt_pk_bf16(a.x, a.y);
        v2f hf; hf.x = __uint_as_float(hi << 16);
                hf.y = __uint_as_float(hi & 0xFFFF0000u);
        const v2f rr = a - hf;
        const int row = (ps + 2 * (k >> 2)) * 16 + q2 * 4 + (k & 3);
        fragA[row * 68 + pc] = hi;
        fragA[4352 + row * 68 + pc] = cvt_pk_bf16(rr.x, rr.y);
      }
  };
  auto mfma = [&](int l, floatx4 C[2][4]) {
    #pragma unroll
    for (int v = 0; v < 2; ++v)
      #pragma unroll
      for (int mt = 0; mt < 4; ++mt) C[v][mt] = (floatx4){0.f, 0.f, 0.f, 0.f};
    #pragma unroll
    for (int kt = 0; kt < 4; ++kt) {
      const uint4* wp0 = wfrag + ((((l * 4 + kt) * 8 + 2 * wv) * 2) << 6);
      FragU B0h, B0l, B1h, B1l;
      B0h.q = wp0[lane];        B0l.q = wp0[64 + lane];
      B1h.q = wp0[128 + lane];  B1l.q = wp0[192 + lane];
      #pragma unroll
      for (int mt = 0; mt < 4; ++mt) {
        const unsigned* fa = fragA + (mt * 16 + m16) * 68 + kt * 16 + q2 * 4;
        FragU Ah, Al;
        Ah.q = *(const uint4*)fa;
        Al.q = *(const uint4*)(fa + 4352);
        C[0][mt] = __builtin_amdgcn_mfma_f32_16x16x32_bf16(Ah.v, B0h.v, C[0][mt], 0, 0, 0);
        C[0][mt] = __builtin_amdgcn_mfma_f32_16x16x32_bf16(Al.v, B0h.v, C[0][mt], 0, 0, 0);
        C[0][mt] = __builtin_amdgcn_mfma_f32_16x16x32_bf16(Ah.v, B0l.v, C[0][mt], 0, 0, 0);
        C[1][mt] = __builtin_amdgcn_mfma_f32_16x16x32_bf16(Ah.v, B1h.v, C[1][mt], 0, 0, 0);
        C[1][mt] = __builtin_amdgcn_mfma_f32_16x16x32_bf16(Al.v, B1h.v, C[1][mt], 0, 0, 0);
        C[1][mt] = __builtin_amdgcn_mfma_f32_16x16x32_bf16(Ah.v, B1l.v, C[1][mt], 0, 0, 0);
      }
    }
  };
  auto residual = [&](int r, int l, floatx4 C[2][4]) {
    const v2f bc = ldv2(b_conv + l * EMB + c0);
    #pragma unroll
    for (int mt = 0; mt < 4; ++mt)
      #pragma unroll
      for (int rr = 0; rr < 4; ++rr) {
        v2f o; o.x = C[0][mt][rr]; o.y = C[1][mt][rr];
        o += bc;
        o.x = fmaxf(o.x, 0.f); o.y = fmaxf(o.y, 0.f);
        X[r][mt][rr] += o;
      }
  };

  // ---- interleaved schedule ----
  v2f accA[2][8], accB[2][8];
  floatx4 C[2][4];

  msg(0, accA);
  pack(accA);
  __syncthreads();
  #pragma unroll 1
  for (int l = 0; l < 5; ++l) {
    mfma(l, C);            // root A — LDS/B latency...
    msg(1, accB);          // ...overlapped by root B's VALU work
    residual(0, l, C);
    __syncthreads();       // A's fragA reads done
    pack(accB);
    __syncthreads();       // B's fragA writes visible
    mfma(l, C);            // root B
    if (l < 4) msg(0, accA);   // overlapped: root A's next-layer messages
    residual(1, l, C);
    __syncthreads();       // B's fragA reads done
    if (l < 4) {
      pack(accA);
      __syncthreads();
    }
  }

  // ---- pooling: both roots share graph g (i0 even) -> one atomic ----
  const v2f wp = ldv2(w_pred + c0);
  float s = 0.f;
  #pragma unroll
  for (int r = 0; r < 2; ++r) {
    v2f p0 = (v2f){-3.4e38f, -3.4e38f}, p1 = p0;
    #pragma unroll
    for (int rr = 0; rr < 4; ++rr) {
      p0.x = fmaxf(p0.x, fmaxf(X[r][0][rr].x, X[r][2][rr].x));
      p0.y = fmaxf(p0.y, fmaxf(X[r][0][rr].y, X[r][2][rr].y));
      p1.x = fmaxf(p1.x, fmaxf(X[r][1][rr].x, X[r][3][rr].x));
      p1.y = fmaxf(p1.y, fmaxf(X[r][1][rr].y, X[r][3][rr].y));
    }
    const v2f pr = (p0 + p1) * wp;
    s += pr.x + pr.y;
  }
  #pragma unroll
  for (int off = 32; off; off >>= 1) s += __shfl_xor(s, off, 64);
  if (lane == 0) atomicAdd(out + g, s);
}

extern "C" void kernel_launch(void* const* d_in, const int* in_sizes, int n_in,
                              void* d_out, int out_size, void* d_ws, size_t ws_size,
                              hipStream_t stream) {
  const int*   x         = (const int*)d_in[0];
  const int*   edge_attr = (const int*)d_in[1];
  const int*   tuplefeat = (const int*)d_in[2];
  const float* emb_x     = (const float*)d_in[12];
  const float* emb_ea    = (const float*)d_in[13];
  const float* emb_tf    = (const float*)d_in[14];
  const float* w_ti      = (const float*)d_in[15];
  const float* b_ti      = (const float*)d_in[16];
  const float* w_conv    = (const float*)d_in[17];
  const float* b_conv    = (const float*)d_in[18];
  const float* w_pred    = (const float*)d_in[19];
  const float* b_pred    = (const float*)d_in[20];
  float* out = (float*)d_out;
  float* lin32 = (float*)d_ws;                               // 32*128 fp32 = 16 KB
  uint4* wfrag = (uint4*)((char*)d_ws + 32 * EMB * 4);       // 320 KB B-fragments

  hipLaunchKernelGGL(prep_kernel, dim3(73), dim3(512), 0, stream,
                     emb_x, w_ti, b_ti, w_conv, b_pred, lin32, wfrag, out);
  hipLaunchKernelGGL(i2gnn_mfma, dim3(2048), dim3(256), 0, stream,
                     x, edge_attr, tuplefeat, emb_x, emb_tf, emb_ea, lin32,
                     b_conv, w_pred, wfrag, out);
}

// Round 15
// 298.921 us; speedup vs baseline: 1.2705x; 1.2705x over previous
//
#include <hip/hip_runtime.h>
#include <hip/hip_bf16.h>

#define EMB 128

typedef __attribute__((ext_vector_type(8))) short short8;   // 8 bf16 (4 VGPRs)
typedef __attribute__((ext_vector_type(4))) float floatx4;  // MFMA C/D
typedef __attribute__((ext_vector_type(2))) float v2f;      // -> v_pk_fma_f32

// 26 valid (ok, di, ol) message combos: deltas = {1,2,-1,-2}, ol = ok+delta in [0,8)
static constexpr int OKv[26] = {0,0,1,1,1,2,2,2,2,3,3,3,3,4,4,4,4,5,5,5,5,6,6,6,7,7};
static constexpr int DIv[26] = {0,1,0,1,2,0,1,2,3,0,1,2,3,0,1,2,3,0,1,2,3,0,2,3,2,3};
static constexpr int OLv[26] = {1,2,2,3,0,3,4,1,0,4,5,2,1,5,6,3,2,6,7,4,3,7,5,4,6,5};

__device__ __forceinline__ v2f ldv2(const float* p) { return *(const v2f*)p; }

// round-to-nearest-even bf16 bits of x, kept in the TOP 16 bits (low 16 zero)
__device__ __forceinline__ unsigned bf16_rne_hi(float x) {
  unsigned u = __float_as_uint(x);
  return (u + 0x7FFFu + ((u >> 16) & 1u)) & 0xFFFF0000u;
}
__device__ __forceinline__ float bf16hi_f(float x) {
  return __uint_as_float(bf16_rne_hi(x));
}
// HW packed cvt: a -> low 16, b -> high 16 (v_cvt_pk_bf16_f32 on gfx950)
__device__ __forceinline__ unsigned cvt_pk_bf16(float a, float b) {
  __hip_bfloat162 h = __float22bfloat162_rn(make_float2(a, b));
  unsigned r; __builtin_memcpy(&r, &h, 4); return r;
}

union FragU { unsigned u[4]; uint4 q; short8 v; };

// LOGICAL CHANNEL PERMUTATION (R9-verified): MFMA C physical position
// (u, n=lane&15) carries logical channel L(u,n) = 2*((u>>1)*16 + n) + (u&1).
// Wave wv computes u in {2wv, 2wv+1} -> lane (wv, m16) holds the ADJACENT
// logical pair c0 = 2*(wv*16+m16), c0+1. Only wfrag bakes the permutation.
//
// SESSION CEILING NOTE (R14): best = this structure at ~232 us main /
// ~300 us total (+~73 us fixed harness gap, R10-measured). Falsified attack
// vectors: occupancy attributes (R1/R6: allocator picks tiny budget, spills
// 0.5-1.6 GB), LDS size & barrier scope (R7/R11), epilogue round-trip (R8/R9),
// bank conflicts (R11: halved, neutral), B-prefetch (R12: compiler already
// pipelines it), VALU width (R13: -6pts VALUBusy, dur unchanged), two-root
// phase interleave (R14: +64 VGPR -> occupancy collapse, +35%). Plateau is
// the per-layer serial chain x VGPR-capped co-residency; all pipes <=35%.

// Fused prep, grid 73 x 512 (R10: prep shape is total-time-neutral):
//  b 0..31  : lin32 row b (4-way f-split + LDS reduce)
//  b 32..71 : w_conv -> B-fragment hi/lo pre-pack with permuted N
//  b 72     : out[g] = b_pred[0]
__global__ __launch_bounds__(512) void prep_kernel(
    const float* __restrict__ emb_x,
    const float* __restrict__ w_ti,
    const float* __restrict__ b_ti,
    const float* __restrict__ w_conv,
    const float* __restrict__ b_pred,
    float* __restrict__ lin32,
    uint4* __restrict__ wfrag,
    float* __restrict__ out) {
  const int b = blockIdx.x, tid = threadIdx.x;
  if (b < 32) {
    __shared__ float red[4][EMB];
    const int e = tid & 127, fh = tid >> 7;      // fh in [0,4)
    const float* xr = emb_x + b * EMB;
    float s = 0.f;
    #pragma unroll 8
    for (int f = fh * 32; f < fh * 32 + 32; ++f)
      s = fmaf(xr[f], w_ti[f * EMB + e], s);
    red[fh][e] = s;
    __syncthreads();
    if (fh == 0)
      lin32[b * EMB + e] =
          b_ti[e] + ((red[0][e] + red[1][e]) + (red[2][e] + red[3][e]));
  } else if (b < 72) {
    const int id   = (b - 32) * 512 + tid;   // 320 frags * 64 lanes = 20480
    const int lane = id & 63;
    const int f    = id >> 6;
    const int pass = f & 1;           // 0 = hi, 1 = lo
    const int u    = (f >> 1) & 7;    // N-tile (physical)
    const int t    = (f >> 4) & 3;    // K-tile
    const int l    = f >> 6;          // layer
    const int q    = lane >> 4, n = lane & 15;
    const int cN   = 2 * ((u >> 1) * 16 + n) + (u & 1);   // logical out channel
    unsigned w[4] = {0u, 0u, 0u, 0u};
    #pragma unroll
    for (int j = 0; j < 8; ++j) {
      const int kk = t * 32 + q * 8 + j;    // logical in channel (canonical)
      float val = w_conv[l * (EMB * EMB) + kk * EMB + cN];
      if (pass) val = val - bf16hi_f(val);
      const unsigned bb = bf16_rne_hi(val);
      w[j >> 1] |= (j & 1) ? bb : (bb >> 16);
    }
    wfrag[id] = make_uint4(w[0], w[1], w[2], w[3]);
  } else {
    if (tid < 64) out[tid] = b_pred[0];
  }
}

// R9 structure + packed fp32 (R13, session best): message pass, hi/lo pack
// residuals, tupleinit and residual+relu on v2f (v_pk_fma_f32 et al).
// No occupancy attribute (R1/R6: forcing a budget -> 0.5-1.6 GB spills).
__global__ __launch_bounds__(256)
void i2gnn_mfma(
    const int* __restrict__ x,
    const int* __restrict__ edge_attr,
    const int* __restrict__ tuplefeat,
    const float* __restrict__ emb_x,
    const float* __restrict__ emb_tf,
    const float* __restrict__ emb_ea,
    const float* __restrict__ lin32,
    const float* __restrict__ b_conv,
    const float* __restrict__ w_pred,
    const uint4* __restrict__ wfrag,
    float* __restrict__ out)
{
  __shared__ __align__(16) unsigned fragA[2 * 64 * 68];   // 34816 B, lo at +4352

  const int tid = threadIdx.x;
  const int wv = tid >> 6, lane = tid & 63;
  const int m16 = lane & 15, q2 = lane >> 4;
  const int pc = wv * 16 + m16;        // logical pair-column this lane produces
  const int c0 = pc * 2;               // logical channels c0, c0+1

  const int i = blockIdx.x;
  const int ibase = i & ~63, io = i & 63;
  const int g = i >> 6;

  // 26 edge attrs (4 bits each) — function of i only
  unsigned pk[4] = {0u, 0u, 0u, 0u};
  #pragma unroll
  for (int m = 0; m < 26; ++m) {
    const int kg = ibase + ((io + OKv[m]) & 63);
    const unsigned a = (unsigned)edge_attr[(kg << 2) + DIv[m]];
    pk[m >> 3] |= a << ((m & 7) * 4);
  }

  // tupleinit in C-layout (packed): X2[mt][r] = v2f over channels (c0, c0+1);
  // pair ps = mt&1 (this lane: 2*q2+ps), k = (mt>>1)*4 + r.
  const int xi = x[i];
  const v2f xe = ldv2(emb_x + xi * EMB + c0);
  v2f lj[2];
  #pragma unroll
  for (int ps = 0; ps < 2; ++ps) {
    const int jn = ibase + ((io + 2 * q2 + ps) & 63);
    lj[ps] = ldv2(lin32 + x[jn] * EMB + c0);
  }
  v2f X2[4][4];   // [mt][r]
  #pragma unroll
  for (int mt = 0; mt < 4; ++mt) {
    const int ps = mt & 1, kb = (mt >> 1) * 4;
    const int t0 = (i * 8 + 2 * q2 + ps) << 3;
    const v2f xl = xe * lj[ps];
    #pragma unroll
    for (int r = 0; r < 4; ++r) {
      const int2 tf2 = *(const int2*)(tuplefeat + 2 * (t0 + kb + r));
      const int row = (c0 < 64) ? tf2.x : tf2.y;   // c0,c0+1 in same half
      const v2f tf = ldv2(emb_tf + row * 64 + (c0 & 63));
      X2[mt][r] = xl * tf;
    }
  }

  for (int l = 0; l < 5; ++l) {
    // ---- message pass, packed fp32 over (c0, c0+1) ----
    v2f acc[2][8];   // [ps][k]
    #pragma unroll
    for (int ps = 0; ps < 2; ++ps)
      #pragma unroll
      for (int k = 0; k < 8; ++k) acc[ps][k] = (v2f){0.f, 0.f};
    #pragma unroll
    for (int m = 0; m < 26; ++m) {
      const unsigned attr = (pk[m >> 3] >> ((m & 7) * 4)) & 15u;
      const v2f e = ldv2(emb_ea + attr * EMB + c0);
      const int ok = OKv[m], ol = OLv[m];
      const int mtb = 2 * (ol >> 2), rl = ol & 3;   // compile-time consts
      acc[0][ok] += X2[mtb + 0][rl] * e;            // v_pk_fma_f32
      acc[1][ok] += X2[mtb + 1][rl] * e;
    }
    // ---- single hi/lo pack (packed residual), straight into A-frag LDS ----
    #pragma unroll
    for (int ps = 0; ps < 2; ++ps)
      #pragma unroll
      for (int k = 0; k < 8; ++k) {
        const v2f a = acc[ps][k];
        const unsigned hi = cvt_pk_bf16(a.x, a.y);
        v2f hf; hf.x = __uint_as_float(hi << 16);
                hf.y = __uint_as_float(hi & 0xFFFF0000u);
        const v2f r = a - hf;                        // v_pk_add_f32
        const int row = (ps + 2 * (k >> 2)) * 16 + q2 * 4 + (k & 3);
        fragA[row * 68 + pc] = hi;
        fragA[4352 + row * 68 + pc] = cvt_pk_bf16(r.x, r.y);
      }
    __syncthreads();

    // ---- MFMA: wave computes u = {2wv, 2wv+1} for all 4 M-tiles ----
    floatx4 C[2][4];
    #pragma unroll
    for (int v = 0; v < 2; ++v)
      #pragma unroll
      for (int mt = 0; mt < 4; ++mt) C[v][mt] = (floatx4){0.f, 0.f, 0.f, 0.f};

    #pragma unroll
    for (int kt = 0; kt < 4; ++kt) {
      const uint4* wp0 = wfrag + ((((l * 4 + kt) * 8 + 2 * wv) * 2) << 6);
      FragU B0h, B0l, B1h, B1l;
      B0h.q = wp0[lane];        B0l.q = wp0[64 + lane];
      B1h.q = wp0[128 + lane];  B1l.q = wp0[192 + lane];
      #pragma unroll
      for (int mt = 0; mt < 4; ++mt) {
        const unsigned* fa = fragA + (mt * 16 + m16) * 68 + kt * 16 + q2 * 4;
        FragU Ah, Al;
        Ah.q = *(const uint4*)fa;
        Al.q = *(const uint4*)(fa + 4352);
        C[0][mt] = __builtin_amdgcn_mfma_f32_16x16x32_bf16(Ah.v, B0h.v, C[0][mt], 0, 0, 0);
        C[0][mt] = __builtin_amdgcn_mfma_f32_16x16x32_bf16(Al.v, B0h.v, C[0][mt], 0, 0, 0);
        C[0][mt] = __builtin_amdgcn_mfma_f32_16x16x32_bf16(Ah.v, B0l.v, C[0][mt], 0, 0, 0);
        C[1][mt] = __builtin_amdgcn_mfma_f32_16x16x32_bf16(Ah.v, B1h.v, C[1][mt], 0, 0, 0);
        C[1][mt] = __builtin_amdgcn_mfma_f32_16x16x32_bf16(Al.v, B1h.v, C[1][mt], 0, 0, 0);
        C[1][mt] = __builtin_amdgcn_mfma_f32_16x16x32_bf16(Ah.v, B1l.v, C[1][mt], 0, 0, 0);
      }
    }
    __syncthreads();   // reads done before next layer overwrites fragA

    // ---- residual + relu, packed: combine C[0]/C[1] into v2f lanes ----
    const v2f bc = ldv2(b_conv + l * EMB + c0);
    #pragma unroll
    for (int mt = 0; mt < 4; ++mt)
      #pragma unroll
      for (int r = 0; r < 4; ++r) {
        v2f o; o.x = C[0][mt][r]; o.y = C[1][mt][r];
        o += bc;                                     // v_pk_add_f32
        o.x = fmaxf(o.x, 0.f); o.y = fmaxf(o.y, 0.f);  // v_pk_max_f32
        X2[mt][r] += o;
      }
  }

  // ---- pooling: max over k per (v, pair), dot w_pred, xor-reduce, atomic ----
  const v2f wp = ldv2(w_pred + c0);
  v2f p0 = (v2f){-3.4e38f, -3.4e38f}, p1 = p0;
  #pragma unroll
  for (int r = 0; r < 4; ++r) {
    p0.x = fmaxf(p0.x, fmaxf(X2[0][r].x, X2[2][r].x));
    p0.y = fmaxf(p0.y, fmaxf(X2[0][r].y, X2[2][r].y));
    p1.x = fmaxf(p1.x, fmaxf(X2[1][r].x, X2[3][r].x));
    p1.y = fmaxf(p1.y, fmaxf(X2[1][r].y, X2[3][r].y));
  }
  const v2f ps = (p0 + p1) * wp;
  float s = ps.x + ps.y;
  #pragma unroll
  for (int off = 32; off; off >>= 1) s += __shfl_xor(s, off, 64);
  if (lane == 0) atomicAdd(out + g, s);
}

extern "C" void kernel_launch(void* const* d_in, const int* in_sizes, int n_in,
                              void* d_out, int out_size, void* d_ws, size_t ws_size,
                              hipStream_t stream) {
  const int*   x         = (const int*)d_in[0];
  const int*   edge_attr = (const int*)d_in[1];
  const int*   tuplefeat = (const int*)d_in[2];
  const float* emb_x     = (const float*)d_in[12];
  const float* emb_ea    = (const float*)d_in[13];
  const float* emb_tf    = (const float*)d_in[14];
  const float* w_ti      = (const float*)d_in[15];
  const float* b_ti      = (const float*)d_in[16];
  const float* w_conv    = (const float*)d_in[17];
  const float* b_conv    = (const float*)d_in[18];
  const float* w_pred    = (const float*)d_in[19];
  const float* b_pred    = (const float*)d_in[20];
  float* out = (float*)d_out;
  float* lin32 = (float*)d_ws;                               // 32*128 fp32 = 16 KB
  uint4* wfrag = (uint4*)((char*)d_ws + 32 * EMB * 4);       // 320 KB B-fragments

  hipLaunchKernelGGL(prep_kernel, dim3(73), dim3(512), 0, stream,
                     emb_x, w_ti, b_ti, w_conv, b_pred, lin32, wfrag, out);
  hipLaunchKernelGGL(i2gnn_mfma, dim3(4096), dim3(256), 0, stream,
                     x, edge_attr, tuplefeat, emb_x, emb_tf, emb_ea, lin32,
                     b_conv, w_pred, wfrag, out);
}